// Round 1
// baseline (1046.248 us; speedup 1.0000x reference)
//
#include <hip/hip_runtime.h>
#include <stdint.h>

// NARM fused pipeline for MI355X (gfx950).
// Phases per time-chunk (TC adaptive to ws_size):
//   k_prep : cast weights->bf16, fold biases, zero carry states (once)
//   k_gi   : gi[t,b,0:768] = x@ [Wih_g;Wih_l]^T + bias (MFMA 16x16x32 bf16)
//   k_scan : dual-GRU recurrence, Whh fragments register-resident, h via LDS
//   k_score: score[t,b] = v1 . sigmoid(A1 h_l + A2 h_g)   (MFMA)
//   k_cum  : cum_{s<=t} score*h_l, capture t in [L_b-4, L_b-1], += h_g

typedef __attribute__((ext_vector_type(8))) short short8;
typedef __attribute__((ext_vector_type(4))) float float4v;

__device__ inline float bf2f(unsigned short u){
  union { unsigned int i; float f; } v; v.i = ((unsigned int)u) << 16; return v.f;
}
__device__ inline unsigned short f2bf(float f){
  union { float f; unsigned int i; } v; v.f = f;
  unsigned int x = v.i;
  return (unsigned short)((x + 0x7fffu + ((x >> 16) & 1u)) >> 16);
}
__device__ inline float sigm(float x){ return 1.0f / (1.0f + __expf(-x)); }
__device__ inline float tanhfast(float x){ return 1.0f - 2.0f / (__expf(2.0f * x) + 1.0f); }

// ---------------- K0: prep ----------------
__global__ void k_prep(const float* Wih_g, const float* Whh_g, const float* bih_g, const float* bhh_g,
                       const float* Wih_l, const float* Whh_l, const float* bih_l, const float* bhh_l,
                       const float* A1, const float* A2,
                       unsigned short* win, unsigned short* whh, unsigned short* a12, float* bc,
                       unsigned short* hl_slot, unsigned short* hg_slot, float* cum)
{
  const long TOTAL = 98304L + 98304 + 32768 + 768 + 131072 + 131072 + 131072;
  long stride = (long)gridDim.x * blockDim.x;
  for (long i = (long)blockIdx.x * blockDim.x + threadIdx.x; i < TOTAL; i += stride) {
    long idx = i;
    if (idx < 98304) { // combined input-proj weights [768][128] bf16
      int g = (int)(idx >> 7), k = (int)(idx & 127);
      float v = (g < 384) ? Wih_g[g * 128 + k] : Wih_l[(g - 384) * 128 + k];
      win[idx] = f2bf(v); continue;
    }
    idx -= 98304;
    if (idx < 98304) { // Whh [2][384][128] bf16
      float v = (idx < 49152) ? Whh_g[idx] : Whh_l[idx - 49152];
      whh[idx] = f2bf(v); continue;
    }
    idx -= 98304;
    if (idx < 32768) { // A1,A2 [2][128][128] bf16
      float v = (idx < 16384) ? A1[idx] : A2[idx - 16384];
      a12[idx] = f2bf(v); continue;
    }
    idx -= 32768;
    if (idx < 768) { // combined bias: bih + (bhh for r,z rows only; bhh_n folded in k_scan)
      int g = (int)idx; float v;
      if (g < 384) v = bih_g[g] + ((g < 256) ? bhh_g[g] : 0.0f);
      else { int g2 = g - 384; v = bih_l[g2] + ((g2 < 256) ? bhh_l[g2] : 0.0f); }
      bc[g] = v; continue;
    }
    idx -= 768;
    if (idx < 131072) { hl_slot[idx] = 0; continue; } // zero h_l carry slot
    idx -= 131072;
    if (idx < 131072) { hg_slot[idx] = 0; continue; } // zero h_g carry slot
    idx -= 131072;
    cum[idx] = 0.0f; // zero cumsum state [1024][128]
  }
}

// ---------------- K1: input-projection GEMM ----------------
// grid (6, tc*16), block 256. C-tile 64(m) x 128(n). K=128 single shot.
__global__ __launch_bounds__(256) void k_gi(const float* __restrict__ x,
                                            const unsigned short* __restrict__ win,
                                            const float* __restrict__ bc,
                                            unsigned short* __restrict__ gi,
                                            int chunk_base_row)
{
  __shared__ __align__(16) unsigned short At[64][136];
  __shared__ __align__(16) unsigned short Bt[128][136];
  int tid = threadIdx.x;

  // stage A: 64 rows x 128 k of x (fp32 -> bf16), coalesced float4
  const float* xbase = x + (size_t)(chunk_base_row + blockIdx.y * 64) * 128;
  #pragma unroll
  for (int i = 0; i < 8; i++) {
    int f4 = i * 256 + tid;                 // 0..2047
    float4 a = ((const float4*)xbase)[f4];
    unsigned int u0 = (unsigned int)f2bf(a.x) | ((unsigned int)f2bf(a.y) << 16);
    unsigned int u1 = (unsigned int)f2bf(a.z) | ((unsigned int)f2bf(a.w) << 16);
    *(uint2*)&At[f4 >> 5][(f4 & 31) * 4] = make_uint2(u0, u1);
  }
  // stage B: 128 rows x 128 k of win (already bf16)
  const unsigned short* wbase = win + (size_t)blockIdx.x * 128 * 128;
  #pragma unroll
  for (int i = 0; i < 8; i++) {
    int f8 = i * 256 + tid;                 // 0..2047
    *(short8*)&Bt[f8 >> 4][(f8 & 15) * 8] = *(const short8*)(wbase + (size_t)f8 * 8);
  }
  __syncthreads();

  int w = tid >> 6, L = tid & 63;
  int l15 = L & 15, q = L >> 4;
  short8 Af[4];
  #pragma unroll
  for (int kf = 0; kf < 4; kf++)
    Af[kf] = *(const short8*)&At[w * 16 + l15][kf * 32 + q * 8];

  float4v acc[8];
  #pragma unroll
  for (int nt = 0; nt < 8; nt++) {
    float4v a = (float4v){0.f, 0.f, 0.f, 0.f};
    #pragma unroll
    for (int kf = 0; kf < 4; kf++) {
      short8 Bf = *(const short8*)&Bt[nt * 16 + l15][kf * 32 + q * 8];
      a = __builtin_amdgcn_mfma_f32_16x16x32_bf16(Af[kf], Bf, a, 0, 0, 0);
    }
    acc[nt] = a;
  }

  int m0 = blockIdx.y * 64 + w * 16;
  #pragma unroll
  for (int nt = 0; nt < 8; nt++) {
    int g = blockIdx.x * 128 + nt * 16 + l15;
    float bcv = bc[g];
    #pragma unroll
    for (int r = 0; r < 4; r++) {
      int m = m0 + q * 4 + r;               // chunk-local row (t_loc*1024 + b)
      gi[(size_t)m * 768 + g] = f2bf(acc[nt][r] + bcv);
    }
  }
}

// ---------------- K2: dual-GRU scan ----------------
// grid 64, block 512 (8 waves). waves 0-3: GRU-g, 4-7: GRU-l. 16 batch rows/block.
__global__ __launch_bounds__(512, 2) void k_scan(const unsigned short* __restrict__ gi,
                                                 const unsigned short* __restrict__ whh,
                                                 const float* __restrict__ bhh_g,
                                                 const float* __restrict__ bhh_l,
                                                 unsigned short* __restrict__ hl_seq,
                                                 unsigned short* __restrict__ hg_seq,
                                                 int tc)
{
  __shared__ __align__(16) unsigned short hbuf[2][2][16][136]; // [pingpong][gru][m][hdim]
  int tid = threadIdx.x;
  int w = tid >> 6, L = tid & 63;
  int gru = w >> 2;            // 0 = g, 1 = l
  int q2 = w & 3;              // wave's column group: cols [q2*32, q2*32+32)
  int l15 = L & 15, q = L >> 4;
  int b0 = blockIdx.x * 16;

  // register-resident Whh B-fragments: [gate][coltile][kfrag]
  short8 Bf[3][2][4];
  const unsigned short* wb = whh + (size_t)gru * 49152;
  #pragma unroll
  for (int G = 0; G < 3; G++)
    #pragma unroll
    for (int ct = 0; ct < 2; ct++) {
      int row = G * 128 + q2 * 32 + ct * 16 + l15;
      #pragma unroll
      for (int kf = 0; kf < 4; kf++)
        Bf[G][ct][kf] = *(const short8*)(wb + (size_t)row * 128 + kf * 32 + q * 8);
    }
  const float* bhh = gru ? bhh_l : bhh_g;
  float bn[2];
  #pragma unroll
  for (int ct = 0; ct < 2; ct++) bn[ct] = bhh[256 + q2 * 32 + ct * 16 + l15];

  unsigned short* myseq = gru ? hl_seq : hg_seq;

  // init from carry slot (tc-1 of previous chunk; zeroed by k_prep for chunk 0)
  float hold[2][4];
  #pragma unroll
  for (int ct = 0; ct < 2; ct++) {
    int j = q2 * 32 + ct * 16 + l15;
    #pragma unroll
    for (int r = 0; r < 4; r++) {
      int m = q * 4 + r;
      unsigned short u = myseq[((size_t)(tc - 1) * 1024 + b0 + m) * 128 + j];
      hold[ct][r] = bf2f(u);
      hbuf[0][gru][m][j] = u;
    }
  }
  __syncthreads();

  int p = 0;
  for (int s = 0; s < tc; s++) {
    // prefetch gi scalars (consumed after MFMA -> latency hidden)
    unsigned short giu[3][2][4];
    const unsigned short* gbase = gi + ((size_t)s * 1024 + b0) * 768 + gru * 384;
    #pragma unroll
    for (int G = 0; G < 3; G++)
      #pragma unroll
      for (int ct = 0; ct < 2; ct++)
        #pragma unroll
        for (int r = 0; r < 4; r++)
          giu[G][ct][r] = gbase[(size_t)(q * 4 + r) * 768 + G * 128 + q2 * 32 + ct * 16 + l15];

    short8 Af[4];
    #pragma unroll
    for (int kf = 0; kf < 4; kf++)
      Af[kf] = *(const short8*)&hbuf[p][gru][l15][kf * 32 + q * 8];

    float4v acc[3][2];
    #pragma unroll
    for (int G = 0; G < 3; G++)
      #pragma unroll
      for (int ct = 0; ct < 2; ct++) {
        float4v a = (float4v){0.f, 0.f, 0.f, 0.f};
        #pragma unroll
        for (int kf = 0; kf < 4; kf++)
          a = __builtin_amdgcn_mfma_f32_16x16x32_bf16(Af[kf], Bf[G][ct][kf], a, 0, 0, 0);
        acc[G][ct] = a;
      }

    #pragma unroll
    for (int ct = 0; ct < 2; ct++) {
      int j = q2 * 32 + ct * 16 + l15;
      #pragma unroll
      for (int r = 0; r < 4; r++) {
        int m = q * 4 + r;
        float gir = bf2f(giu[0][ct][r]);
        float giz = bf2f(giu[1][ct][r]);
        float gin = bf2f(giu[2][ct][r]);
        float rr = sigm(gir + acc[0][ct][r]);
        float zz = sigm(giz + acc[1][ct][r]);
        float nn = tanhfast(gin + rr * (acc[2][ct][r] + bn[ct])); // bhh_n inside r*(...)
        float hn = (1.0f - zz) * nn + zz * hold[ct][r];
        hold[ct][r] = hn;
        unsigned short hu = f2bf(hn);
        hbuf[1 - p][gru][m][j] = hu;
        myseq[((size_t)s * 1024 + b0 + m) * 128 + j] = hu;
      }
    }
    p ^= 1;
    __syncthreads();
  }
}

// ---------------- K3a: attention score ----------------
// grid tc*16, block 256 (4 waves, 1 m-tile of 16 (t,b)-rows each)
__global__ __launch_bounds__(256) void k_score(const unsigned short* __restrict__ hl_seq,
                                               const unsigned short* __restrict__ hg_seq,
                                               const unsigned short* __restrict__ a12,
                                               const float* __restrict__ v1,
                                               float* __restrict__ score, int tc)
{
  __shared__ __align__(16) unsigned short Mt[128][136];
  int tid = threadIdx.x;
  int w = tid >> 6, L = tid & 63;
  int l15 = L & 15, q = L >> 4;
  int tile = blockIdx.x * 4 + w;
  int s = tile >> 6;
  int b0 = (tile & 63) * 16;

  short8 Fl[4], Fg[4];
  #pragma unroll
  for (int kf = 0; kf < 4; kf++) {
    size_t base = ((size_t)s * 1024 + b0 + l15) * 128 + kf * 32 + q * 8;
    Fl[kf] = *(const short8*)(hl_seq + base);
    Fg[kf] = *(const short8*)(hg_seq + base);
  }
  float4v acc[8];
  #pragma unroll
  for (int nt = 0; nt < 8; nt++) acc[nt] = (float4v){0.f, 0.f, 0.f, 0.f};

  // phase 1: A1 * h_l
  #pragma unroll
  for (int i = 0; i < 8; i++) {
    int f8 = i * 256 + tid;
    *(short8*)&Mt[f8 >> 4][(f8 & 15) * 8] = *(const short8*)(a12 + (size_t)f8 * 8);
  }
  __syncthreads();
  #pragma unroll
  for (int nt = 0; nt < 8; nt++)
    #pragma unroll
    for (int kf = 0; kf < 4; kf++)
      acc[nt] = __builtin_amdgcn_mfma_f32_16x16x32_bf16(
          Fl[kf], *(const short8*)&Mt[nt * 16 + l15][kf * 32 + q * 8], acc[nt], 0, 0, 0);
  __syncthreads();
  // phase 2: A2 * h_g
  #pragma unroll
  for (int i = 0; i < 8; i++) {
    int f8 = i * 256 + tid;
    *(short8*)&Mt[f8 >> 4][(f8 & 15) * 8] = *(const short8*)(a12 + 16384 + (size_t)f8 * 8);
  }
  __syncthreads();
  #pragma unroll
  for (int nt = 0; nt < 8; nt++)
    #pragma unroll
    for (int kf = 0; kf < 4; kf++)
      acc[nt] = __builtin_amdgcn_mfma_f32_16x16x32_bf16(
          Fg[kf], *(const short8*)&Mt[nt * 16 + l15][kf * 32 + q * 8], acc[nt], 0, 0, 0);

  float v1v[8];
  #pragma unroll
  for (int nt = 0; nt < 8; nt++) v1v[nt] = v1[nt * 16 + l15];

  float p4[4];
  #pragma unroll
  for (int r = 0; r < 4; r++) {
    float sum = 0.f;
    #pragma unroll
    for (int nt = 0; nt < 8; nt++) sum += v1v[nt] * sigm(acc[nt][r]);
    sum += __shfl_xor(sum, 1, 16);
    sum += __shfl_xor(sum, 2, 16);
    sum += __shfl_xor(sum, 4, 16);
    sum += __shfl_xor(sum, 8, 16);
    p4[r] = sum;
  }
  if (l15 == 0) {
    #pragma unroll
    for (int r = 0; r < 4; r++)
      score[(size_t)s * 1024 + b0 + q * 4 + r] = p4[r];
  }
}

// ---------------- K3b: cumsum + capture ----------------
// grid 512, block 256: thread = (b, h)
__global__ __launch_bounds__(256) void k_cum(const float* __restrict__ score,
                                             const unsigned short* __restrict__ hl_seq,
                                             const unsigned short* __restrict__ hg_seq,
                                             const int* __restrict__ lengths,
                                             float* __restrict__ cum,
                                             float* __restrict__ out, int tc, int t0)
{
  int tid = threadIdx.x;
  int b = blockIdx.x * 2 + (tid >> 7);
  int j = tid & 127;
  float c = cum[(size_t)b * 128 + j];
  int cap0 = lengths[b] - 4; // capture window [cap0, cap0+3], always within [0,199]
  for (int s = 0; s < tc; s++) {
    size_t row = (size_t)s * 1024 + b;
    c += score[row] * bf2f(hl_seq[row * 128 + j]);
    int d = (t0 + s) - cap0;
    if (d >= 0 && d < 4)
      out[((size_t)b * 4 + d) * 128 + j] = c + bf2f(hg_seq[row * 128 + j]);
  }
  cum[(size_t)b * 128 + j] = c;
}

// ---------------- launch ----------------
extern "C" void kernel_launch(void* const* d_in, const int* in_sizes, int n_in,
                              void* d_out, int out_size, void* d_ws, size_t ws_size,
                              hipStream_t stream)
{
  const float* x     = (const float*)d_in[0];
  const int* lengths = (const int*)d_in[1];
  const float* Wih_g = (const float*)d_in[2];
  const float* Whh_g = (const float*)d_in[3];
  const float* bih_g = (const float*)d_in[4];
  const float* bhh_g = (const float*)d_in[5];
  const float* Wih_l = (const float*)d_in[6];
  const float* Whh_l = (const float*)d_in[7];
  const float* bih_l = (const float*)d_in[8];
  const float* bhh_l = (const float*)d_in[9];
  const float* A1    = (const float*)d_in[10];
  const float* A2    = (const float*)d_in[11];
  const float* v1    = (const float*)d_in[12];
  float* out = (float*)d_out;

  // pick largest time-chunk that fits the workspace
  const int cands[6] = {50, 25, 10, 5, 2, 1};
  const size_t fixed = 196608 + 196608 + 65536 + 3072 + 524288;
  int tc = 0;
  for (int i = 0; i < 6; i++) {
    int T = cands[i];
    size_t need = (size_t)T * 1024 * 768 * 2   // gi bf16
                + 2 * (size_t)T * 1024 * 128 * 2 // h_l, h_g bf16
                + (size_t)T * 1024 * 4          // score fp32
                + fixed;
    if (need <= ws_size) { tc = T; break; }
  }
  if (!tc) return;

  char* wsb = (char*)d_ws;
  size_t o = 0;
  unsigned short* gi  = (unsigned short*)(wsb + o); o += (size_t)tc * 1024 * 768 * 2;
  unsigned short* hl  = (unsigned short*)(wsb + o); o += (size_t)tc * 1024 * 128 * 2;
  unsigned short* hg  = (unsigned short*)(wsb + o); o += (size_t)tc * 1024 * 128 * 2;
  unsigned short* win = (unsigned short*)(wsb + o); o += 196608;
  unsigned short* whh = (unsigned short*)(wsb + o); o += 196608;
  unsigned short* a12 = (unsigned short*)(wsb + o); o += 65536;
  float* bc    = (float*)(wsb + o); o += 3072;
  float* score = (float*)(wsb + o); o += (size_t)tc * 1024 * 4;
  float* cum   = (float*)(wsb + o);

  unsigned short* hl_slot = hl + (size_t)(tc - 1) * 1024 * 128;
  unsigned short* hg_slot = hg + (size_t)(tc - 1) * 1024 * 128;

  k_prep<<<128, 256, 0, stream>>>(Wih_g, Whh_g, bih_g, bhh_g, Wih_l, Whh_l, bih_l, bhh_l,
                                  A1, A2, win, whh, a12, bc, hl_slot, hg_slot, cum);
  int nch = 200 / tc;
  for (int c = 0; c < nch; c++) {
    k_gi<<<dim3(6, tc * 16), 256, 0, stream>>>(x, win, bc, gi, c * tc * 1024);
    k_scan<<<64, 512, 0, stream>>>(gi, whh, bhh_g, bhh_l, hl, hg, tc);
    k_score<<<tc * 16, 256, 0, stream>>>(hl, hg, a12, v1, score, tc);
    k_cum<<<512, 256, 0, stream>>>(score, hl, hg, lengths, cum, out, tc, c * tc);
  }
}

// Round 2
// 426.472 us; speedup vs baseline: 2.4533x; 2.4533x over previous
//
#include <hip/hip_runtime.h>
#include <stdint.h>

// NARM fused pipeline v2 for MI355X (gfx950).
//   k_prep : zero carry slots + cumsum state (only)
//   k_scan : dual-GRU recurrence with input projection FUSED (x prefetched
//            one step ahead; Wih/Whh B-fragments register-resident)
//   k_score: score[t,b] = v1 . sigmoid(A1 h_l + A2 h_g)   (MFMA)
//   k_cum  : LDS-staged cumsum of score*h_l, capture t in [L_b-4, L_b-1], +h_g

typedef __attribute__((ext_vector_type(8))) short short8;
typedef __attribute__((ext_vector_type(4))) float float4v;

__device__ inline float bf2f(unsigned short u){
  union { unsigned int i; float f; } v; v.i = ((unsigned int)u) << 16; return v.f;
}
__device__ inline unsigned short f2bf(float f){
  union { float f; unsigned int i; } v; v.f = f;
  unsigned int x = v.i;
  return (unsigned short)((x + 0x7fffu + ((x >> 16) & 1u)) >> 16);
}
__device__ inline unsigned int pack2(float a, float b){
  return (unsigned int)f2bf(a) | ((unsigned int)f2bf(b) << 16);
}
__device__ inline float sigm(float x){ return __builtin_amdgcn_rcpf(1.0f + __expf(-x)); }
__device__ inline float tanhfast(float x){ return 1.0f - 2.0f * __builtin_amdgcn_rcpf(__expf(2.0f * x) + 1.0f); }

// ---------------- K0: prep (zero carries + cum) ----------------
__global__ void k_prep(unsigned short* hl_slot, unsigned short* hg_slot, float* cum)
{
  int i = blockIdx.x * blockDim.x + threadIdx.x;   // grid 512*256 = 131072
  hl_slot[i] = 0;
  hg_slot[i] = 0;
  cum[i] = 0.0f;
}

// ---------------- K1: fused dual-GRU scan ----------------
// grid 128 = (64 batch-groups x 2 GRUs), block 512 (8 waves, 16 cols each).
__global__ __launch_bounds__(512, 2) void k_scan(
    const float* __restrict__ x,
    const float* __restrict__ Wih_g, const float* __restrict__ Whh_g,
    const float* __restrict__ bih_g, const float* __restrict__ bhh_g,
    const float* __restrict__ Wih_l, const float* __restrict__ Whh_l,
    const float* __restrict__ bih_l, const float* __restrict__ bhh_l,
    unsigned short* __restrict__ hl_seq, unsigned short* __restrict__ hg_seq,
    int tc, int t0)
{
  __shared__ __align__(16) unsigned short hbuf[2][16][136];
  __shared__ __align__(16) unsigned short xbuf[2][16][136];
  int tid = threadIdx.x;
  int w = tid >> 6, L = tid & 63, l15 = L & 15, q = L >> 4;
  int gru = blockIdx.x & 1;                 // 0 = g, 1 = l
  int b0 = (blockIdx.x >> 1) * 16;
  const float* Wih = gru ? Wih_l : Wih_g;
  const float* Whh = gru ? Whh_l : Whh_g;
  const float* bih = gru ? bih_l : bih_g;
  const float* bhh = gru ? bhh_l : bhh_g;
  unsigned short* myseq = gru ? hl_seq : hg_seq;

  int col = w * 16 + l15;                   // this lane's output column

  // register-resident weight B-fragments (fp32 -> bf16 once per launch)
  short8 Wi[3][4], Wh[3][4];
  #pragma unroll
  for (int G = 0; G < 3; G++) {
    int row = G * 128 + col;
    #pragma unroll
    for (int kf = 0; kf < 4; kf++) {
      const float4* p0 = (const float4*)(Wih + (size_t)row * 128 + kf * 32 + q * 8);
      const float4* p1 = (const float4*)(Whh + (size_t)row * 128 + kf * 32 + q * 8);
      float4 a0 = p0[0], a1 = p0[1], b0f = p1[0], b1f = p1[1];
      short8 si, sh;
      si[0]=(short)f2bf(a0.x); si[1]=(short)f2bf(a0.y); si[2]=(short)f2bf(a0.z); si[3]=(short)f2bf(a0.w);
      si[4]=(short)f2bf(a1.x); si[5]=(short)f2bf(a1.y); si[6]=(short)f2bf(a1.z); si[7]=(short)f2bf(a1.w);
      sh[0]=(short)f2bf(b0f.x); sh[1]=(short)f2bf(b0f.y); sh[2]=(short)f2bf(b0f.z); sh[3]=(short)f2bf(b0f.w);
      sh[4]=(short)f2bf(b1f.x); sh[5]=(short)f2bf(b1f.y); sh[6]=(short)f2bf(b1f.z); sh[7]=(short)f2bf(b1f.w);
      Wi[G][kf] = si; Wh[G][kf] = sh;
    }
  }
  float br  = bih[col]       + bhh[col];
  float bz  = bih[128 + col] + bhh[128 + col];
  float bin = bih[256 + col];               // bhh_n stays inside r*( ) per PyTorch GRU
  float bnh = bhh[256 + col];

  // init h from carry slot (zeroed by k_prep for chunk 0)
  float hold[4];
  #pragma unroll
  for (int r = 0; r < 4; r++) {
    int m = q * 4 + r;
    unsigned short u = myseq[((size_t)(tc - 1) * 1024 + b0 + m) * 128 + col];
    hold[r] = bf2f(u);
    hbuf[0][m][col] = u;
  }
  // stage x(t0), prefetch x(t0+1)
  {
    float4 x0 = ((const float4*)(x + ((size_t)t0 * 1024 + b0) * 128))[tid];
    int row = tid >> 5, c4 = (tid & 31) * 4;
    *(uint2*)&xbuf[0][row][c4] = make_uint2(pack2(x0.x, x0.y), pack2(x0.z, x0.w));
  }
  int tn = t0 + (tc > 1 ? 1 : 0);
  float4 xr = ((const float4*)(x + ((size_t)tn * 1024 + b0) * 128))[tid];
  __syncthreads();

  int p = 0;
  for (int s = 0; s < tc; s++) {
    // A-fragments from LDS
    short8 Ah[4], Ax[4];
    #pragma unroll
    for (int kf = 0; kf < 4; kf++) {
      Ah[kf] = *(const short8*)&hbuf[p][l15][kf * 32 + q * 8];
      Ax[kf] = *(const short8*)&xbuf[p][l15][kf * 32 + q * 8];
    }
    // commit prefetched x(s+1) to the other buffer (safe: last read pre-barrier)
    if (s + 1 < tc) {
      int row = tid >> 5, c4 = (tid & 31) * 4;
      *(uint2*)&xbuf[1 - p][row][c4] = make_uint2(pack2(xr.x, xr.y), pack2(xr.z, xr.w));
    }
    // issue prefetch of x(s+2) — a full step of latency cover
    {
      int t2 = t0 + (s + 2 < tc ? s + 2 : tc - 1);
      xr = ((const float4*)(x + ((size_t)t2 * 1024 + b0) * 128))[tid];
    }
    // MFMA: r,z accumulate x-proj + h-proj; n keeps them separate
    float4v arz0 = (float4v){0.f,0.f,0.f,0.f};
    float4v arz1 = (float4v){0.f,0.f,0.f,0.f};
    float4v anx  = (float4v){0.f,0.f,0.f,0.f};
    float4v anh  = (float4v){0.f,0.f,0.f,0.f};
    #pragma unroll
    for (int kf = 0; kf < 4; kf++) arz0 = __builtin_amdgcn_mfma_f32_16x16x32_bf16(Ax[kf], Wi[0][kf], arz0, 0,0,0);
    #pragma unroll
    for (int kf = 0; kf < 4; kf++) arz0 = __builtin_amdgcn_mfma_f32_16x16x32_bf16(Ah[kf], Wh[0][kf], arz0, 0,0,0);
    #pragma unroll
    for (int kf = 0; kf < 4; kf++) arz1 = __builtin_amdgcn_mfma_f32_16x16x32_bf16(Ax[kf], Wi[1][kf], arz1, 0,0,0);
    #pragma unroll
    for (int kf = 0; kf < 4; kf++) arz1 = __builtin_amdgcn_mfma_f32_16x16x32_bf16(Ah[kf], Wh[1][kf], arz1, 0,0,0);
    #pragma unroll
    for (int kf = 0; kf < 4; kf++) anx  = __builtin_amdgcn_mfma_f32_16x16x32_bf16(Ax[kf], Wi[2][kf], anx,  0,0,0);
    #pragma unroll
    for (int kf = 0; kf < 4; kf++) anh  = __builtin_amdgcn_mfma_f32_16x16x32_bf16(Ah[kf], Wh[2][kf], anh,  0,0,0);

    // gates (fp32 state in registers)
    #pragma unroll
    for (int r = 0; r < 4; r++) {
      int m = q * 4 + r;
      float rr = sigm(arz0[r] + br);
      float zz = sigm(arz1[r] + bz);
      float nn = tanhfast(anx[r] + bin + rr * (anh[r] + bnh));
      float hn = nn + zz * (hold[r] - nn);
      hold[r] = hn;
      unsigned short hu = f2bf(hn);
      hbuf[1 - p][m][col] = hu;
      myseq[((size_t)s * 1024 + b0 + m) * 128 + col] = hu;
    }
    p ^= 1;
    __syncthreads();
  }
}

// ---------------- K2: attention score ----------------
// grid tc*16, block 256 (4 waves, one 16-row (t,b)-tile each)
__global__ __launch_bounds__(256) void k_score(const unsigned short* __restrict__ hl_seq,
                                               const unsigned short* __restrict__ hg_seq,
                                               const float* __restrict__ A1,
                                               const float* __restrict__ A2,
                                               const float* __restrict__ v1,
                                               float* __restrict__ score, int tc)
{
  __shared__ __align__(16) unsigned short Mt[128][136];
  int tid = threadIdx.x;
  int w = tid >> 6, L = tid & 63;
  int l15 = L & 15, q = L >> 4;
  int tile = blockIdx.x * 4 + w;
  int s = tile >> 6;
  int b0 = (tile & 63) * 16;

  short8 Fl[4], Fg[4];
  #pragma unroll
  for (int kf = 0; kf < 4; kf++) {
    size_t base = ((size_t)s * 1024 + b0 + l15) * 128 + kf * 32 + q * 8;
    Fl[kf] = *(const short8*)(hl_seq + base);
    Fg[kf] = *(const short8*)(hg_seq + base);
  }
  float4v acc[8];
  #pragma unroll
  for (int nt = 0; nt < 8; nt++) acc[nt] = (float4v){0.f, 0.f, 0.f, 0.f};

  // phase 1: A1 * h_l  (stage fp32 -> bf16)
  #pragma unroll
  for (int it = 0; it < 16; it++) {
    int f4 = it * 256 + tid;                 // 0..4095
    float4 a = ((const float4*)A1)[f4];
    *(uint2*)&Mt[f4 >> 5][(f4 & 31) * 4] = make_uint2(pack2(a.x, a.y), pack2(a.z, a.w));
  }
  __syncthreads();
  #pragma unroll
  for (int nt = 0; nt < 8; nt++)
    #pragma unroll
    for (int kf = 0; kf < 4; kf++)
      acc[nt] = __builtin_amdgcn_mfma_f32_16x16x32_bf16(
          Fl[kf], *(const short8*)&Mt[nt * 16 + l15][kf * 32 + q * 8], acc[nt], 0, 0, 0);
  __syncthreads();
  // phase 2: A2 * h_g
  #pragma unroll
  for (int it = 0; it < 16; it++) {
    int f4 = it * 256 + tid;
    float4 a = ((const float4*)A2)[f4];
    *(uint2*)&Mt[f4 >> 5][(f4 & 31) * 4] = make_uint2(pack2(a.x, a.y), pack2(a.z, a.w));
  }
  __syncthreads();
  #pragma unroll
  for (int nt = 0; nt < 8; nt++)
    #pragma unroll
    for (int kf = 0; kf < 4; kf++)
      acc[nt] = __builtin_amdgcn_mfma_f32_16x16x32_bf16(
          Fg[kf], *(const short8*)&Mt[nt * 16 + l15][kf * 32 + q * 8], acc[nt], 0, 0, 0);

  float v1v[8];
  #pragma unroll
  for (int nt = 0; nt < 8; nt++) v1v[nt] = v1[nt * 16 + l15];

  float p4[4];
  #pragma unroll
  for (int r = 0; r < 4; r++) {
    float sum = 0.f;
    #pragma unroll
    for (int nt = 0; nt < 8; nt++) sum += v1v[nt] * sigm(acc[nt][r]);
    sum += __shfl_xor(sum, 1, 16);
    sum += __shfl_xor(sum, 2, 16);
    sum += __shfl_xor(sum, 4, 16);
    sum += __shfl_xor(sum, 8, 16);
    p4[r] = sum;
  }
  if (l15 == 0) {
    #pragma unroll
    for (int r = 0; r < 4; r++)
      score[(size_t)(b0 + q * 4 + r) * tc + s] = p4[r];   // layout [b][tc]
  }
}

// ---------------- K3: cumsum + capture (LDS-staged) ----------------
// grid 512, block 256: 2 batch rows/block, thread = (b2, j)
__global__ __launch_bounds__(256) void k_cum(const float* __restrict__ score,
                                             const unsigned short* __restrict__ hl_seq,
                                             const unsigned short* __restrict__ hg_seq,
                                             const int* __restrict__ lengths,
                                             float* __restrict__ cum,
                                             float* __restrict__ out, int tc, int t0)
{
  __shared__ __align__(16) unsigned short hlL[100 * 256];  // [s_seg][b2*128+j]
  __shared__ float scL[2][100];
  int tid = threadIdx.x;
  int b2 = tid >> 7, j = tid & 127;
  int b0 = blockIdx.x * 2;
  int b = b0 + b2;
  int base = b2 * 128 + j;

  float c = cum[(size_t)b * 128 + j];
  int cap0 = lengths[b] - 4;                // capture window [cap0, cap0+3] in [0,199]

  // preload the (<=4) h_g capture values that fall in this chunk
  float hgv[4];
  #pragma unroll
  for (int d = 0; d < 4; d++) {
    int sl = cap0 + d - t0;
    hgv[d] = (sl >= 0 && sl < tc) ? bf2f(hg_seq[((size_t)sl * 1024 + b) * 128 + j]) : 0.f;
  }

  for (int seg = 0; seg < tc; seg += 100) {
    int len = (tc - seg < 100) ? (tc - seg) : 100;
    __syncthreads();                         // protect LDS reuse across segments
    // stage hl rows [seg, seg+len) : coalesced short8
    for (int f8 = tid; f8 < len * 32; f8 += 256) {
      int sl = f8 >> 5, r8 = f8 & 31;
      *(short8*)&hlL[(size_t)f8 * 8] =
          *(const short8*)(hl_seq + ((size_t)(seg + sl) * 1024 + b0) * 128 + r8 * 8);
    }
    // stage score rows (contiguous per b: layout [b][tc])
    for (int i = tid; i < 2 * len; i += 256) {
      int bb = (i >= len) ? 1 : 0;
      int sl = i - bb * len;
      scL[bb][sl] = score[(size_t)(b0 + bb) * tc + seg + sl];
    }
    __syncthreads();

    int sl = 0;
    for (; sl + 5 <= len; sl += 5) {
      float h[5], sc[5];
      #pragma unroll
      for (int k = 0; k < 5; k++) {
        h[k] = bf2f(hlL[(size_t)(sl + k) * 256 + base]);
        sc[k] = scL[b2][sl + k];
      }
      #pragma unroll
      for (int k = 0; k < 5; k++) {
        c += sc[k] * h[k];
        int d = (t0 + seg + sl + k) - cap0;
        if ((unsigned)d < 4u)
          out[((size_t)b * 4 + d) * 128 + j] = c + hgv[d];
      }
    }
    for (; sl < len; sl++) {
      c += scL[b2][sl] * bf2f(hlL[(size_t)sl * 256 + base]);
      int d = (t0 + seg + sl) - cap0;
      if ((unsigned)d < 4u)
        out[((size_t)b * 4 + d) * 128 + j] = c + hgv[d];
    }
  }
  cum[(size_t)b * 128 + j] = c;
}

// ---------------- launch ----------------
extern "C" void kernel_launch(void* const* d_in, const int* in_sizes, int n_in,
                              void* d_out, int out_size, void* d_ws, size_t ws_size,
                              hipStream_t stream)
{
  const float* x     = (const float*)d_in[0];
  const int* lengths = (const int*)d_in[1];
  const float* Wih_g = (const float*)d_in[2];
  const float* Whh_g = (const float*)d_in[3];
  const float* bih_g = (const float*)d_in[4];
  const float* bhh_g = (const float*)d_in[5];
  const float* Wih_l = (const float*)d_in[6];
  const float* Whh_l = (const float*)d_in[7];
  const float* bih_l = (const float*)d_in[8];
  const float* bhh_l = (const float*)d_in[9];
  const float* A1    = (const float*)d_in[10];
  const float* A2    = (const float*)d_in[11];
  const float* v1    = (const float*)d_in[12];
  float* out = (float*)d_out;

  // pick largest time-chunk that fits the workspace (no gi buffer anymore)
  const int cands[8] = {200, 100, 50, 25, 10, 5, 2, 1};
  int tc = 0;
  for (int i = 0; i < 8; i++) {
    int T = cands[i];
    size_t need = 2 * (size_t)T * 1024 * 128 * 2   // hl, hg bf16
                + (size_t)T * 1024 * 4             // score fp32 [b][tc]
                + 524288;                          // cum fp32
    if (need <= ws_size) { tc = T; break; }
  }
  if (!tc) return;

  char* wsb = (char*)d_ws;
  size_t o = 0;
  unsigned short* hl  = (unsigned short*)(wsb + o); o += (size_t)tc * 1024 * 128 * 2;
  unsigned short* hg  = (unsigned short*)(wsb + o); o += (size_t)tc * 1024 * 128 * 2;
  float* score = (float*)(wsb + o); o += (size_t)tc * 1024 * 4;
  float* cum   = (float*)(wsb + o);

  unsigned short* hl_slot = hl + (size_t)(tc - 1) * 1024 * 128;
  unsigned short* hg_slot = hg + (size_t)(tc - 1) * 1024 * 128;

  k_prep<<<512, 256, 0, stream>>>(hl_slot, hg_slot, cum);
  int nch = 200 / tc;
  for (int c = 0; c < nch; c++) {
    k_scan<<<128, 512, 0, stream>>>(x, Wih_g, Whh_g, bih_g, bhh_g,
                                    Wih_l, Whh_l, bih_l, bhh_l, hl, hg, tc, c * tc);
    k_score<<<tc * 16, 256, 0, stream>>>(hl, hg, A1, A2, v1, score, tc);
    k_cum<<<512, 256, 0, stream>>>(score, hl, hg, lengths, cum, out, tc, c * tc);
  }
}